// Round 17
// baseline (122.968 us; speedup 1.0000x reference)
//
#include <hip/hip_runtime.h>
#include <math.h>

#define D 128
#define NCLS 32
#define TSLOT 16
#define CHUNK 256  // labels per sort block

typedef float f32x16 __attribute__((ext_vector_type(16)));
typedef short bf16x8 __attribute__((ext_vector_type(8)));

// ---------------- zero counters ----------------
__global__ void zero_k(int* hist) {
  int t = threadIdx.x;
  if (t < NCLS) hist[t] = 0;
}

// ---------------- per-block label histogram (+ global hist) ----------------
__global__ __launch_bounds__(64) void hist_blk_k(const int* __restrict__ label, int M,
                                                 int NB, int* __restrict__ blkhist_t,
                                                 int* __restrict__ hist) {
  __shared__ int h[NCLS];
  const int lane = threadIdx.x;
  const int b = blockIdx.x;
  if (lane < NCLS) h[lane] = 0;
  __syncthreads();
  const int s0 = b * CHUNK;
#pragma unroll
  for (int it = 0; it < CHUNK / 64; ++it) {
    int i = s0 + it * 64 + lane;
    if (i < M) atomicAdd(&h[label[i]], 1);
  }
  __syncthreads();
  if (lane < NCLS) {
    blkhist_t[lane * NB + b] = h[lane];
    atomicAdd(&hist[lane], h[lane]);
  }
}

// ---------------- exclusive prefix over classes ----------------
__global__ void prefix_k(const int* __restrict__ hist, int* __restrict__ cstart) {
  if (threadIdx.x == 0) {
    int run = 0;
    for (int j = 0; j < NCLS; ++j) { cstart[j] = run; run += hist[j]; }
    cstart[NCLS] = run;
  }
}

// ---------------- per-class scan over blocks: base_t[j][b] ----------------
__global__ __launch_bounds__(64) void base_k(const int* __restrict__ blkhist_t,
                                             const int* __restrict__ cstart, int NB,
                                             int* __restrict__ base_t) {
  const int j = blockIdx.x;
  const int lane = threadIdx.x;
  const int K = (NB + 63) / 64;
  int vals[32];
  int run = 0;
  for (int k = 0; k < K; ++k) {
    int b = lane * K + k;
    int v = (b < NB) ? blkhist_t[j * NB + b] : 0;
    vals[k] = v;
    run += v;
  }
  int incl = run;
  for (int off = 1; off < 64; off <<= 1) {
    int o = __shfl_up(incl, off);
    if (lane >= off) incl += o;
  }
  int pos = cstart[j] + (incl - run);
  for (int k = 0; k < K; ++k) {
    int b = lane * K + k;
    if (b < NB) base_t[j * NB + b] = pos;
    pos += vals[k];
  }
}

// ---------------- stable, atomic-free scatter (1 wave / block) ----------------
__global__ __launch_bounds__(64) void scatter2_k(const int* __restrict__ label, int M,
                                                 int NB, const int* __restrict__ base_t,
                                                 int* __restrict__ idxbuf) {
  __shared__ int cur[NCLS];
  const int b = blockIdx.x;
  const int lane = threadIdx.x;
  if (lane < NCLS) cur[lane] = base_t[lane * NB + b];
  __syncthreads();
  const int s0 = b * CHUNK;
#pragma unroll
  for (int it = 0; it < CHUNK / 64; ++it) {
    int i = s0 + it * 64 + lane;
    int j = (i < M) ? label[i] : -1;
    unsigned long long mask = 0;
#pragma unroll
    for (int q = 0; q < NCLS; ++q) {
      unsigned long long mm = __ballot(j == q);
      if (j == q) mask = mm;
    }
    if (j >= 0) {
      int myoff = __popcll(mask & ((1ull << lane) - 1ull));
      int basec = cur[j];
      idxbuf[basec + myoff] = i;
      if (myoff == 0) cur[j] = basec + __popcll(mask);
    }
    __syncthreads();
  }
}

// ---------------- fp32 -> (hi, lo) bf16 split, RNE ----------------
__device__ inline void bsplit(float x, short& hi, short& lo) {
  unsigned u = __float_as_uint(x);
  unsigned rh = u + 0x7fffu + ((u >> 16) & 1u);
  unsigned short h = (unsigned short)(rh >> 16);
  float hf = __uint_as_float((unsigned)h << 16);
  float l = x - hf;  // exact
  unsigned ul = __float_as_uint(l);
  unsigned rl = ul + 0x7fffu + ((ul >> 16) & 1u);
  hi = (short)h;
  lo = (short)(rl >> 16);
}

// Raw barrier: orders LDS (lgkmcnt only) without draining in-flight global
// loads (vmcnt). __syncthreads would emit s_waitcnt vmcnt(0) and kill the
// gather pipeline. sched_barrier(0) pins ordering (guide rule #18).
__device__ __forceinline__ void rawbar() {
  asm volatile("s_waitcnt lgkmcnt(0)" ::: "memory");
  __builtin_amdgcn_s_barrier();
  __builtin_amdgcn_sched_barrier(0);
}

// ---------------- per-class Gram via bf16-split MFMA ----------------
// R16 structure + raw barriers + 2-chunk-deep Z pipeline (pvA/pvB static sets,
// loop unrolled x2). Z(ch+2T) is issued one full iteration before use; compiler
// emits counted vmcnt at the stage-time use, so gather latency hides under a
// whole iteration of MFMA + barriers instead of ~150 cycles.
__global__ __launch_bounds__(1024, 8) void cov_k(const float* __restrict__ Z,
                                                 const int* __restrict__ idxbuf,
                                                 const int* __restrict__ hist,
                                                 const int* __restrict__ cstart,
                                                 float* __restrict__ partials) {
  __shared__ __attribute__((aligned(16))) char arena[33792];
  char* const ThiB = arena;
  char* const TloB = arena + 16896;

  const int b = blockIdx.x;
  const int cls = b / TSLOT, slot = b % TSLOT;
  const int t = threadIdx.x;
  const int lane = t & 63;
  const int w = t >> 6;
  const int r = w >> 2;  // A row-strip 0..3
  const int cq = w & 3;  // B col-strip 0..3

  const int col4 = t & 31;  // stages cols 4*col4 .. +3
  const int rg = t >> 5;    // stages rows rg*2, rg*2+1 (k dim)
  const int wbase = (((rg >> 3) * 4 + (col4 >> 3)) * 2 + ((rg >> 2) & 1)) * 528 +
                    (col4 & 7) * 16 + (rg & 3) * 4;

  const int mj = hist[cls];
  const int seg0 = cstart[cls];
  const int segend = seg0 + mj;
  const int nch = (mj + 63) / 64;

  f32x16 acc;
#pragma unroll
  for (int i = 0; i < 16; ++i) acc[i] = 0.f;

  const int n = lane & 31;
  const int poff = ((n >> 2) + 8 * (n & 3)) * 16 + (lane >> 5) * 528;

  float4 pvA[2], pvB[2];
  int iA0 = 0, iA1 = 0;  // idx values for chunk ch+2T (A-parity refill)
  int iB0 = 0, iB1 = 0;  // idx values for chunk ch+3T (B-parity refill)

  // ---- prologue: pvA = Z(slot), pvB = Z(slot+T); prefetch idx(slot+2T/3T)
  {
    const int c0 = slot;
    const int r0 = seg0 + c0 * 64;
    int i0 = 0, i1 = 0;
    if (c0 < nch) {
      int g0 = r0 + rg * 2, g1 = g0 + 1;
      if (g0 < segend) i0 = idxbuf[g0];
      if (g1 < segend) i1 = idxbuf[g1];
      pvA[0] = (g0 < segend) ? *(const float4*)(Z + (size_t)i0 * D + col4 * 4)
                             : make_float4(0.f, 0.f, 0.f, 0.f);
      pvA[1] = (g1 < segend) ? *(const float4*)(Z + (size_t)i1 * D + col4 * 4)
                             : make_float4(0.f, 0.f, 0.f, 0.f);
    } else {
      pvA[0] = make_float4(0.f, 0.f, 0.f, 0.f);
      pvA[1] = make_float4(0.f, 0.f, 0.f, 0.f);
    }
    const int c1 = slot + TSLOT;
    const int r1 = seg0 + c1 * 64;
    int j0 = 0, j1 = 0;
    if (c1 < nch) {
      int g0 = r1 + rg * 2, g1 = g0 + 1;
      if (g0 < segend) j0 = idxbuf[g0];
      if (g1 < segend) j1 = idxbuf[g1];
      pvB[0] = (g0 < segend) ? *(const float4*)(Z + (size_t)j0 * D + col4 * 4)
                             : make_float4(0.f, 0.f, 0.f, 0.f);
      pvB[1] = (g1 < segend) ? *(const float4*)(Z + (size_t)j1 * D + col4 * 4)
                             : make_float4(0.f, 0.f, 0.f, 0.f);
    } else {
      pvB[0] = make_float4(0.f, 0.f, 0.f, 0.f);
      pvB[1] = make_float4(0.f, 0.f, 0.f, 0.f);
    }
    const int c2 = slot + 2 * TSLOT;
    const int r2 = seg0 + c2 * 64;
    if (c2 < nch) {
      int g0 = r2 + rg * 2, g1 = g0 + 1;
      if (g0 < segend) iA0 = idxbuf[g0];
      if (g1 < segend) iA1 = idxbuf[g1];
    }
    const int c3 = slot + 3 * TSLOT;
    const int r3 = seg0 + c3 * 64;
    if (c3 < nch) {
      int g0 = r3 + rg * 2, g1 = g0 + 1;
      if (g0 < segend) iB0 = idxbuf[g0];
      if (g1 < segend) iB1 = idxbuf[g1];
    }
  }

#pragma unroll 1
  for (int ch = slot; ch < nch; ch += 2 * TSLOT) {
    // ============ half A: process chunk ch (pvA) ============
    rawbar();  // arena free (lgkm only; pvB/idx loads stay in flight)
    {
      float xs[2][4];
      xs[0][0] = pvA[0].x; xs[0][1] = pvA[0].y; xs[0][2] = pvA[0].z; xs[0][3] = pvA[0].w;
      xs[1][0] = pvA[1].x; xs[1][1] = pvA[1].y; xs[1][2] = pvA[1].z; xs[1][3] = pvA[1].w;
#pragma unroll
      for (int j = 0; j < 4; ++j) {
        short h0, l0, h1, l1;
        bsplit(xs[0][j], h0, l0);
        bsplit(xs[1][j], h1, l1);
        *(short2*)(ThiB + wbase + j * 128) = make_short2(h0, h1);
        *(short2*)(TloB + wbase + j * 128) = make_short2(l0, l1);
      }
    }
    rawbar();  // arena staged
    {  // refill pvA with Z(ch+2T) via resident iA; then iA = idx(ch+4T)
      const int chn = ch + 2 * TSLOT;
      const int rn = seg0 + chn * 64;
      int g0 = rn + rg * 2, g1 = g0 + 1;
      bool v0 = (chn < nch) && (g0 < segend);
      bool v1 = (chn < nch) && (g1 < segend);
      pvA[0] = v0 ? *(const float4*)(Z + (size_t)iA0 * D + col4 * 4)
                  : make_float4(0.f, 0.f, 0.f, 0.f);
      pvA[1] = v1 ? *(const float4*)(Z + (size_t)iA1 * D + col4 * 4)
                  : make_float4(0.f, 0.f, 0.f, 0.f);
      const int c4 = ch + 4 * TSLOT;
      const int r4 = seg0 + c4 * 64;
      if (c4 < nch) {
        int h0 = r4 + rg * 2, h1 = h0 + 1;
        if (h0 < segend) iA0 = idxbuf[h0];
        if (h1 < segend) iA1 = idxbuf[h1];
      }
    }
#pragma unroll
    for (int kk = 0; kk < 4; ++kk) {
      const int ab = (kk * 4 + r) * 1056 + poff;
      const int bb = (kk * 4 + cq) * 1056 + poff;
      bf16x8 ahi = *(const bf16x8*)(ThiB + ab);
      bf16x8 alo = *(const bf16x8*)(TloB + ab);
      bf16x8 bhi = *(const bf16x8*)(ThiB + bb);
      bf16x8 blo = *(const bf16x8*)(TloB + bb);
      acc = __builtin_amdgcn_mfma_f32_32x32x16_bf16(ahi, bhi, acc, 0, 0, 0);
      acc = __builtin_amdgcn_mfma_f32_32x32x16_bf16(ahi, blo, acc, 0, 0, 0);
      acc = __builtin_amdgcn_mfma_f32_32x32x16_bf16(alo, bhi, acc, 0, 0, 0);
    }
    // ============ half B: process chunk ch+T (pvB; zeros if ch+T >= nch) ====
    rawbar();  // arena free
    {
      float xs[2][4];
      xs[0][0] = pvB[0].x; xs[0][1] = pvB[0].y; xs[0][2] = pvB[0].z; xs[0][3] = pvB[0].w;
      xs[1][0] = pvB[1].x; xs[1][1] = pvB[1].y; xs[1][2] = pvB[1].z; xs[1][3] = pvB[1].w;
#pragma unroll
      for (int j = 0; j < 4; ++j) {
        short h0, l0, h1, l1;
        bsplit(xs[0][j], h0, l0);
        bsplit(xs[1][j], h1, l1);
        *(short2*)(ThiB + wbase + j * 128) = make_short2(h0, h1);
        *(short2*)(TloB + wbase + j * 128) = make_short2(l0, l1);
      }
    }
    rawbar();  // arena staged
    {  // refill pvB with Z(ch+3T) via resident iB; then iB = idx(ch+5T)
      const int chn = ch + 3 * TSLOT;
      const int rn = seg0 + chn * 64;
      int g0 = rn + rg * 2, g1 = g0 + 1;
      bool v0 = (chn < nch) && (g0 < segend);
      bool v1 = (chn < nch) && (g1 < segend);
      pvB[0] = v0 ? *(const float4*)(Z + (size_t)iB0 * D + col4 * 4)
                  : make_float4(0.f, 0.f, 0.f, 0.f);
      pvB[1] = v1 ? *(const float4*)(Z + (size_t)iB1 * D + col4 * 4)
                  : make_float4(0.f, 0.f, 0.f, 0.f);
      const int c5 = ch + 5 * TSLOT;
      const int r5 = seg0 + c5 * 64;
      if (c5 < nch) {
        int h0 = r5 + rg * 2, h1 = h0 + 1;
        if (h0 < segend) iB0 = idxbuf[h0];
        if (h1 < segend) iB1 = idxbuf[h1];
      }
    }
#pragma unroll
    for (int kk = 0; kk < 4; ++kk) {
      const int ab = (kk * 4 + r) * 1056 + poff;
      const int bb = (kk * 4 + cq) * 1056 + poff;
      bf16x8 ahi = *(const bf16x8*)(ThiB + ab);
      bf16x8 alo = *(const bf16x8*)(TloB + ab);
      bf16x8 bhi = *(const bf16x8*)(ThiB + bb);
      bf16x8 blo = *(const bf16x8*)(TloB + bb);
      acc = __builtin_amdgcn_mfma_f32_32x32x16_bf16(ahi, bhi, acc, 0, 0, 0);
      acc = __builtin_amdgcn_mfma_f32_32x32x16_bf16(ahi, blo, acc, 0, 0, 0);
      acc = __builtin_amdgcn_mfma_f32_32x32x16_bf16(alo, bhi, acc, 0, 0, 0);
    }
  }

  // epilogue: direct coalesced global write (partial already symmetric-complete)
  size_t base = (size_t)b * (D * D);
#pragma unroll
  for (int i = 0; i < 16; ++i) {
    int prow = r * 32 + (i & 3) + 8 * (i >> 2) + 4 * (lane >> 5);
    int qcol = cq * 32 + (lane & 31);
    partials[base + (size_t)prow * D + qcol] = acc[i];
  }
}

// ---------------- reduce partials -> 32 class covs + total cov ----------------
__global__ void reduce_k(const float* __restrict__ partials, float* __restrict__ covs) {
  int e = blockIdx.x * blockDim.x + threadIdx.x;
  double tot = 0.0;
  for (int j = 0; j < NCLS; ++j) {
    double s = 0.0;
    for (int t = 0; t < TSLOT; ++t)
      s += (double)partials[(size_t)(j * TSLOT + t) * (D * D) + e];
    covs[(size_t)j * (D * D) + e] = (float)s;
    tot += s;
  }
  covs[(size_t)NCLS * (D * D) + e] = (float)tot;
}

// ---------------- blocked Cholesky logdet ----------------
__global__ __launch_bounds__(256, 1) void chol_k(const float* __restrict__ covs,
                                                 const int* __restrict__ hist,
                                                 int Mtot, double* __restrict__ results) {
  __shared__ float As[128][132];
  __shared__ float PlT[32][36];  // PlT[i][jj] = L11[jj][i]
  __shared__ float invd[32];
  __shared__ float colbuf[32];
  __shared__ double red[64];
  __shared__ __attribute__((aligned(16))) short Thi[96 * 40];  // 40-short (80B) pitch
  __shared__ __attribute__((aligned(16))) short Tlo[96 * 40];
  const int j = blockIdx.x;
  const float* A = covs + (size_t)j * (D * D);
  const int tid = threadIdx.x;
  const int lane = tid & 63;
  const int wv = tid >> 6;

#pragma unroll
  for (int it = 0; it < 16; ++it) {
    int e = it * 1024 + tid * 4;
    int r = e >> 7, c = e & 127;
    *(float4*)&As[r][c] = *(const float4*)&A[e];
  }
  __syncthreads();

  double lda = 0.0;
#pragma unroll 1
  for (int p = 0; p < 4; ++p) {
    const int pbase = p * 32;
    const int N2 = 96 - pbase;
    if (wv == 0) {
      const int l = lane & 31;
      float row[32];
#pragma unroll
      for (int c4 = 0; c4 < 8; ++c4) {
        float4 v = *(const float4*)&As[pbase + l][pbase + c4 * 4];
        row[c4 * 4 + 0] = v.x; row[c4 * 4 + 1] = v.y;
        row[c4 * 4 + 2] = v.z; row[c4 * 4 + 3] = v.w;
      }
      float mypiv = 1.f, myinv = 0.f;
#pragma unroll
      for (int k = 0; k < 32; ++k) {
        colbuf[l] = row[k];
        float cb[32];
#pragma unroll
        for (int q = 0; q < 8; ++q) {
          float4 v = *(const float4*)&colbuf[q * 4];
          cb[q * 4 + 0] = v.x; cb[q * 4 + 1] = v.y;
          cb[q * 4 + 2] = v.z; cb[q * 4 + 3] = v.w;
        }
        float piv = cb[k];
        float inv = rsqrtf(piv);
        inv = inv * (1.5f - 0.5f * piv * inv * inv);
        if (lane == k) { mypiv = piv; myinv = inv; }
        float tmul = row[k] * (inv * inv);
#pragma unroll
        for (int c = k + 1; c < 32; ++c)
          row[c] = fmaf(-tmul, cb[c], row[c]);
        row[k] *= inv;
      }
      if (lane < 32) {
#pragma unroll
        for (int c = 0; c < 32; ++c) PlT[c][lane] = row[c];
        invd[lane] = myinv;
      }
      lda += log((double)mypiv);
    }
    __syncthreads();
    if (tid < N2) {
      const int R = pbase + 32 + tid;
      float s[32];
#pragma unroll
      for (int c4 = 0; c4 < 8; ++c4) {
        float4 v = *(const float4*)&As[R][pbase + c4 * 4];
        s[c4 * 4 + 0] = v.x; s[c4 * 4 + 1] = v.y;
        s[c4 * 4 + 2] = v.z; s[c4 * 4 + 3] = v.w;
      }
#pragma unroll
      for (int i = 0; i < 32; ++i) {
        float xi = s[i] * invd[i];
        s[i] = xi;
#pragma unroll
        for (int jj = i + 1; jj < 32; ++jj)
          s[jj] = fmaf(-xi, PlT[i][jj], s[jj]);
      }
      unsigned hp[16], lp[16];
#pragma unroll
      for (int q = 0; q < 16; ++q) {
        short ha, la, hb, lb;
        bsplit(s[2 * q], ha, la);
        bsplit(s[2 * q + 1], hb, lb);
        hp[q] = (unsigned)(unsigned short)ha | ((unsigned)(unsigned short)hb << 16);
        lp[q] = (unsigned)(unsigned short)la | ((unsigned)(unsigned short)lb << 16);
      }
#pragma unroll
      for (int q = 0; q < 4; ++q) {
        *(int4*)&Thi[tid * 40 + q * 8] =
            make_int4(hp[4 * q], hp[4 * q + 1], hp[4 * q + 2], hp[4 * q + 3]);
        *(int4*)&Tlo[tid * 40 + q * 8] =
            make_int4(lp[4 * q], lp[4 * q + 1], lp[4 * q + 2], lp[4 * q + 3]);
      }
    }
    __syncthreads();
    const int nstr = N2 >> 5;
    if (wv < nstr) {
      const int l31 = lane & 31;
      const int h = lane >> 5;
      const int arow = wv * 32 + l31;
#pragma unroll 1
      for (int ct = 0; ct < nstr; ++ct) {
        const int brow = ct * 32 + l31;
        f32x16 acc;
#pragma unroll
        for (int i = 0; i < 16; ++i) acc[i] = 0.f;
#pragma unroll
        for (int ks = 0; ks < 2; ++ks) {
          const int off = ks * 16 + h * 8;
          bf16x8 ahi = *(const bf16x8*)&Thi[arow * 40 + off];
          bf16x8 alo = *(const bf16x8*)&Tlo[arow * 40 + off];
          bf16x8 bhi = *(const bf16x8*)&Thi[brow * 40 + off];
          bf16x8 blo = *(const bf16x8*)&Tlo[brow * 40 + off];
          acc = __builtin_amdgcn_mfma_f32_32x32x16_bf16(ahi, bhi, acc, 0, 0, 0);
          acc = __builtin_amdgcn_mfma_f32_32x32x16_bf16(ahi, blo, acc, 0, 0, 0);
          acc = __builtin_amdgcn_mfma_f32_32x32x16_bf16(alo, bhi, acc, 0, 0, 0);
        }
#pragma unroll
        for (int i = 0; i < 16; ++i) {
          int rr = pbase + 32 + wv * 32 + (i & 3) + 8 * (i >> 2) + 4 * h;
          int cc = pbase + 32 + ct * 32 + l31;
          As[rr][cc] -= acc[i];
        }
      }
    }
    __syncthreads();
  }

  if (wv == 0) red[lane] = lda;
  __syncthreads();
  if (tid == 0) {
    double lsum = 0.0;
    for (int i = 0; i < 64; ++i) lsum += red[i];
    if (j < NCLS) {
      int mj = hist[j];
      double res = 0.0;
      if (mj > 0) {
        double cj = (double)D / ((double)mj * 0.01);
        res = ((double)D * log(cj) + lsum) * (double)mj / (2.0 * (double)Mtot);
      }
      results[j] = res;
    } else {
      double c = (double)D / ((double)Mtot * 0.01);
      results[NCLS] = ((double)D * log(c) + lsum) * 0.5;
    }
  }
}

// ---------------- combine ----------------
__global__ void final_k(const double* __restrict__ results, float* __restrict__ out) {
  if (threadIdx.x == 0 && blockIdx.x == 0) {
    double s = 0.0;
    for (int j = 0; j < NCLS; ++j) s += results[j];
    out[0] = (float)(s - results[NCLS]);
  }
}

extern "C" void kernel_launch(void* const* d_in, const int* in_sizes, int n_in,
                              void* d_out, int out_size, void* d_ws, size_t ws_size,
                              hipStream_t stream) {
  const float* Z = (const float*)d_in[0];
  const int* label = (const int*)d_in[1];
  const int Mtot = in_sizes[1];
  float* out = (float*)d_out;
  const int NB = (Mtot + CHUNK - 1) / CHUNK;

  char* ws = (char*)d_ws;
  int* hist = (int*)(ws + 0);
  int* cstart = (int*)(ws + 256);
  double* results = (double*)(ws + 512);
  int* idxbuf = (int*)(ws + 1024);
  float* partials = (float*)(ws + 1024 + (size_t)Mtot * sizeof(int));
  float* covs = partials + (size_t)NCLS * TSLOT * D * D;
  int* blkhist_t = (int*)partials;  // aliased, dead before cov_k
  int* base_t = blkhist_t + (size_t)NCLS * NB;

  zero_k<<<1, 64, 0, stream>>>(hist);
  hist_blk_k<<<NB, 64, 0, stream>>>(label, Mtot, NB, blkhist_t, hist);
  prefix_k<<<1, 64, 0, stream>>>(hist, cstart);
  base_k<<<NCLS, 64, 0, stream>>>(blkhist_t, cstart, NB, base_t);
  scatter2_k<<<NB, 64, 0, stream>>>(label, Mtot, NB, base_t, idxbuf);
  cov_k<<<NCLS * TSLOT, 1024, 0, stream>>>(Z, idxbuf, hist, cstart, partials);
  reduce_k<<<(D * D) / 256, 256, 0, stream>>>(partials, covs);
  chol_k<<<NCLS + 1, 256, 0, stream>>>(covs, hist, Mtot, results);
  final_k<<<1, 64, 0, stream>>>(results, out);
}

// Round 18
// 118.479 us; speedup vs baseline: 1.0379x; 1.0379x over previous
//
#include <hip/hip_runtime.h>
#include <math.h>

#define D 128
#define NCLS 32
#define TSLOT 16
#define CHUNK 256  // labels per sort block

typedef float f32x16 __attribute__((ext_vector_type(16)));
typedef short bf16x8 __attribute__((ext_vector_type(8)));

// ---------------- zero counters ----------------
__global__ void zero_k(int* hist) {
  int t = threadIdx.x;
  if (t < NCLS) hist[t] = 0;
}

// ---------------- per-block label histogram (+ global hist) ----------------
__global__ __launch_bounds__(64) void hist_blk_k(const int* __restrict__ label, int M,
                                                 int NB, int* __restrict__ blkhist_t,
                                                 int* __restrict__ hist) {
  __shared__ int h[NCLS];
  const int lane = threadIdx.x;
  const int b = blockIdx.x;
  if (lane < NCLS) h[lane] = 0;
  __syncthreads();
  const int s0 = b * CHUNK;
#pragma unroll
  for (int it = 0; it < CHUNK / 64; ++it) {
    int i = s0 + it * 64 + lane;
    if (i < M) atomicAdd(&h[label[i]], 1);
  }
  __syncthreads();
  if (lane < NCLS) {
    blkhist_t[lane * NB + b] = h[lane];
    atomicAdd(&hist[lane], h[lane]);
  }
}

// ---------------- exclusive prefix over classes ----------------
__global__ void prefix_k(const int* __restrict__ hist, int* __restrict__ cstart) {
  if (threadIdx.x == 0) {
    int run = 0;
    for (int j = 0; j < NCLS; ++j) { cstart[j] = run; run += hist[j]; }
    cstart[NCLS] = run;
  }
}

// ---------------- per-class scan over blocks: base_t[j][b] ----------------
__global__ __launch_bounds__(64) void base_k(const int* __restrict__ blkhist_t,
                                             const int* __restrict__ cstart, int NB,
                                             int* __restrict__ base_t) {
  const int j = blockIdx.x;
  const int lane = threadIdx.x;
  const int K = (NB + 63) / 64;
  int vals[32];
  int run = 0;
  for (int k = 0; k < K; ++k) {
    int b = lane * K + k;
    int v = (b < NB) ? blkhist_t[j * NB + b] : 0;
    vals[k] = v;
    run += v;
  }
  int incl = run;
  for (int off = 1; off < 64; off <<= 1) {
    int o = __shfl_up(incl, off);
    if (lane >= off) incl += o;
  }
  int pos = cstart[j] + (incl - run);
  for (int k = 0; k < K; ++k) {
    int b = lane * K + k;
    if (b < NB) base_t[j * NB + b] = pos;
    pos += vals[k];
  }
}

// ---------------- stable, atomic-free scatter (1 wave / block) ----------------
__global__ __launch_bounds__(64) void scatter2_k(const int* __restrict__ label, int M,
                                                 int NB, const int* __restrict__ base_t,
                                                 int* __restrict__ idxbuf) {
  __shared__ int cur[NCLS];
  const int b = blockIdx.x;
  const int lane = threadIdx.x;
  if (lane < NCLS) cur[lane] = base_t[lane * NB + b];
  __syncthreads();
  const int s0 = b * CHUNK;
#pragma unroll
  for (int it = 0; it < CHUNK / 64; ++it) {
    int i = s0 + it * 64 + lane;
    int j = (i < M) ? label[i] : -1;
    unsigned long long mask = 0;
#pragma unroll
    for (int q = 0; q < NCLS; ++q) {
      unsigned long long mm = __ballot(j == q);
      if (j == q) mask = mm;
    }
    if (j >= 0) {
      int myoff = __popcll(mask & ((1ull << lane) - 1ull));
      int basec = cur[j];
      idxbuf[basec + myoff] = i;
      if (myoff == 0) cur[j] = basec + __popcll(mask);
    }
    __syncthreads();
  }
}

// ---------------- fp32 -> (hi, lo) bf16 split, RNE ----------------
__device__ inline void bsplit(float x, short& hi, short& lo) {
  unsigned u = __float_as_uint(x);
  unsigned rh = u + 0x7fffu + ((u >> 16) & 1u);
  unsigned short h = (unsigned short)(rh >> 16);
  float hf = __uint_as_float((unsigned)h << 16);
  float l = x - hf;  // exact
  unsigned ul = __float_as_uint(l);
  unsigned rl = ul + 0x7fffu + ((ul >> 16) & 1u);
  hi = (short)h;
  lo = (short)(rl >> 16);
}

// ---------------- per-class Gram via bf16-split MFMA ----------------
// 1024 threads (16 waves) per block -> 2 blocks/CU = 32 waves/CU (full wave
// occupancy). Each wave owns ONE 32x32 output tile (r = w>>2, cq = w&3) and
// accumulates the symmetric-complete hi.hi^T + hi.lo^T + lo.hi^T directly.
// Fragment-ordered LDS arena (33.8 KB, region pitch 528 B, slot bijection
// p=(n>>2)+8(n&3)). Pipeline per 64-row chunk: barrier(arena free) -> stage
// -> barrier(staged) -> issue Z(c+1) [idx already resident] + idx(c+2) -> MFMA.
__global__ __launch_bounds__(1024, 8) void cov_k(const float* __restrict__ Z,
                                                 const int* __restrict__ idxbuf,
                                                 const int* __restrict__ hist,
                                                 const int* __restrict__ cstart,
                                                 float* __restrict__ partials) {
  __shared__ __attribute__((aligned(16))) char arena[33792];
  char* const ThiB = arena;
  char* const TloB = arena + 16896;

  const int b = blockIdx.x;
  const int cls = b / TSLOT, slot = b % TSLOT;
  const int t = threadIdx.x;
  const int lane = t & 63;
  const int w = t >> 6;
  const int r = w >> 2;   // A row-strip 0..3
  const int cq = w & 3;   // B col-strip 0..3

  const int col4 = t & 31;  // stages cols 4*col4 .. +3
  const int rg = t >> 5;    // stages rows rg*2, rg*2+1 (k dim)
  const int wbase = (((rg >> 3) * 4 + (col4 >> 3)) * 2 + ((rg >> 2) & 1)) * 528 +
                    (col4 & 7) * 16 + (rg & 3) * 4;

  const int mj = hist[cls];
  const int seg0 = cstart[cls];
  const int segend = seg0 + mj;
  const int nch = (mj + 63) / 64;

  f32x16 acc;
#pragma unroll
  for (int i = 0; i < 16; ++i) acc[i] = 0.f;

  const int n = lane & 31;
  const int poff = ((n >> 2) + 8 * (n & 3)) * 16 + (lane >> 5) * 528;

  float4 pv[2];
  int idxn0 = 0, idxn1 = 0;
  {
    const int ch = slot;
    const int r0 = seg0 + ch * 64;
    int i0 = 0, i1 = 0;
    if (ch < nch) {
      int g0 = r0 + rg * 2, g1 = r0 + rg * 2 + 1;
      if (g0 < segend) i0 = idxbuf[g0];
      if (g1 < segend) i1 = idxbuf[g1];
      pv[0] = (g0 < segend) ? *(const float4*)(Z + (size_t)i0 * D + col4 * 4)
                            : make_float4(0.f, 0.f, 0.f, 0.f);
      pv[1] = (g1 < segend) ? *(const float4*)(Z + (size_t)i1 * D + col4 * 4)
                            : make_float4(0.f, 0.f, 0.f, 0.f);
    } else {
      pv[0] = make_float4(0.f, 0.f, 0.f, 0.f);
      pv[1] = make_float4(0.f, 0.f, 0.f, 0.f);
    }
    const int chn = ch + TSLOT;
    const int r1 = seg0 + chn * 64;
    if (chn < nch) {
      int g0 = r1 + rg * 2, g1 = r1 + rg * 2 + 1;
      if (g0 < segend) idxn0 = idxbuf[g0];
      if (g1 < segend) idxn1 = idxbuf[g1];
    }
  }

#pragma unroll 1
  for (int ch = slot; ch < nch; ch += TSLOT) {
    __syncthreads();  // arena free (prior MFMA done by all waves)
    {
      float xs[2][4];
      xs[0][0] = pv[0].x; xs[0][1] = pv[0].y; xs[0][2] = pv[0].z; xs[0][3] = pv[0].w;
      xs[1][0] = pv[1].x; xs[1][1] = pv[1].y; xs[1][2] = pv[1].z; xs[1][3] = pv[1].w;
#pragma unroll
      for (int j = 0; j < 4; ++j) {
        short h0, l0, h1, l1;
        bsplit(xs[0][j], h0, l0);
        bsplit(xs[1][j], h1, l1);
        *(short2*)(ThiB + wbase + j * 128) = make_short2(h0, h1);
        *(short2*)(TloB + wbase + j * 128) = make_short2(l0, l1);
      }
    }
    __syncthreads();  // arena staged by all waves
    {
      const int chn = ch + TSLOT;
      const int r1 = seg0 + chn * 64;
      int g0 = r1 + rg * 2, g1 = r1 + rg * 2 + 1;
      bool v0 = (chn < nch) && (g0 < segend);
      bool v1 = (chn < nch) && (g1 < segend);
      pv[0] = v0 ? *(const float4*)(Z + (size_t)idxn0 * D + col4 * 4)
                 : make_float4(0.f, 0.f, 0.f, 0.f);
      pv[1] = v1 ? *(const float4*)(Z + (size_t)idxn1 * D + col4 * 4)
                 : make_float4(0.f, 0.f, 0.f, 0.f);
      const int chn2 = ch + 2 * TSLOT;
      const int r2 = seg0 + chn2 * 64;
      if (chn2 < nch) {
        int h0 = r2 + rg * 2, h1 = r2 + rg * 2 + 1;
        if (h0 < segend) idxn0 = idxbuf[h0];
        if (h1 < segend) idxn1 = idxbuf[h1];
      }
    }
#pragma unroll
    for (int kk = 0; kk < 4; ++kk) {
      const int ab = (kk * 4 + r) * 1056 + poff;
      const int bb = (kk * 4 + cq) * 1056 + poff;
      bf16x8 ahi = *(const bf16x8*)(ThiB + ab);
      bf16x8 alo = *(const bf16x8*)(TloB + ab);
      bf16x8 bhi = *(const bf16x8*)(ThiB + bb);
      bf16x8 blo = *(const bf16x8*)(TloB + bb);
      acc = __builtin_amdgcn_mfma_f32_32x32x16_bf16(ahi, bhi, acc, 0, 0, 0);
      acc = __builtin_amdgcn_mfma_f32_32x32x16_bf16(ahi, blo, acc, 0, 0, 0);
      acc = __builtin_amdgcn_mfma_f32_32x32x16_bf16(alo, bhi, acc, 0, 0, 0);
    }
  }

  size_t base = (size_t)b * (D * D);
#pragma unroll
  for (int i = 0; i < 16; ++i) {
    int prow = r * 32 + (i & 3) + 8 * (i >> 2) + 4 * (lane >> 5);
    int qcol = cq * 32 + (lane & 31);
    partials[base + (size_t)prow * D + qcol] = acc[i];
  }
}

// ---------------- reduce partials -> 32 class covs + total cov ----------------
__global__ void reduce_k(const float* __restrict__ partials, float* __restrict__ covs) {
  int e = blockIdx.x * blockDim.x + threadIdx.x;
  double tot = 0.0;
  for (int j = 0; j < NCLS; ++j) {
    double s = 0.0;
    for (int t = 0; t < TSLOT; ++t)
      s += (double)partials[(size_t)(j * TSLOT + t) * (D * D) + e];
    covs[(size_t)j * (D * D) + e] = (float)s;
    tot += s;
  }
  covs[(size_t)NCLS * (D * D) + e] = (float)tot;
}

// ---------------- blocked Cholesky logdet ----------------
// One block (256 thr) per matrix. Diag: wave 0, LDS-broadcast. Solve: i-outer
// substitution, solved row kept in regs. Trailing: MFMA via hi/lo bf16 split.
__global__ __launch_bounds__(256, 1) void chol_k(const float* __restrict__ covs,
                                                 const int* __restrict__ hist,
                                                 int Mtot, double* __restrict__ results) {
  __shared__ float As[128][132];
  __shared__ float PlT[32][36];  // PlT[i][jj] = L11[jj][i]
  __shared__ float invd[32];
  __shared__ float colbuf[32];
  __shared__ double red[64];
  __shared__ __attribute__((aligned(16))) short Thi[96 * 40];  // 40-short (80B) pitch
  __shared__ __attribute__((aligned(16))) short Tlo[96 * 40];
  const int j = blockIdx.x;
  const float* A = covs + (size_t)j * (D * D);
  const int tid = threadIdx.x;
  const int lane = tid & 63;
  const int wv = tid >> 6;

#pragma unroll
  for (int it = 0; it < 16; ++it) {
    int e = it * 1024 + tid * 4;
    int r = e >> 7, c = e & 127;
    *(float4*)&As[r][c] = *(const float4*)&A[e];
  }
  __syncthreads();

  double lda = 0.0;
#pragma unroll 1
  for (int p = 0; p < 4; ++p) {
    const int pbase = p * 32;
    const int N2 = 96 - pbase;
    if (wv == 0) {
      const int l = lane & 31;
      float row[32];
#pragma unroll
      for (int c4 = 0; c4 < 8; ++c4) {
        float4 v = *(const float4*)&As[pbase + l][pbase + c4 * 4];
        row[c4 * 4 + 0] = v.x; row[c4 * 4 + 1] = v.y;
        row[c4 * 4 + 2] = v.z; row[c4 * 4 + 3] = v.w;
      }
      float mypiv = 1.f, myinv = 0.f;
#pragma unroll
      for (int k = 0; k < 32; ++k) {
        colbuf[l] = row[k];
        float cb[32];
#pragma unroll
        for (int q = 0; q < 8; ++q) {
          float4 v = *(const float4*)&colbuf[q * 4];
          cb[q * 4 + 0] = v.x; cb[q * 4 + 1] = v.y;
          cb[q * 4 + 2] = v.z; cb[q * 4 + 3] = v.w;
        }
        float piv = cb[k];
        float inv = rsqrtf(piv);
        inv = inv * (1.5f - 0.5f * piv * inv * inv);
        if (lane == k) { mypiv = piv; myinv = inv; }
        float tmul = row[k] * (inv * inv);
#pragma unroll
        for (int c = k + 1; c < 32; ++c)
          row[c] = fmaf(-tmul, cb[c], row[c]);
        row[k] *= inv;
      }
      if (lane < 32) {
#pragma unroll
        for (int c = 0; c < 32; ++c) PlT[c][lane] = row[c];
        invd[lane] = myinv;
      }
      lda += log((double)mypiv);
    }
    __syncthreads();
    if (tid < N2) {
      const int R = pbase + 32 + tid;
      float s[32];
#pragma unroll
      for (int c4 = 0; c4 < 8; ++c4) {
        float4 v = *(const float4*)&As[R][pbase + c4 * 4];
        s[c4 * 4 + 0] = v.x; s[c4 * 4 + 1] = v.y;
        s[c4 * 4 + 2] = v.z; s[c4 * 4 + 3] = v.w;
      }
#pragma unroll
      for (int i = 0; i < 32; ++i) {
        float xi = s[i] * invd[i];
        s[i] = xi;
#pragma unroll
        for (int jj = i + 1; jj < 32; ++jj)
          s[jj] = fmaf(-xi, PlT[i][jj], s[jj]);
      }
      unsigned hp[16], lp[16];
#pragma unroll
      for (int q = 0; q < 16; ++q) {
        short ha, la, hb, lb;
        bsplit(s[2 * q], ha, la);
        bsplit(s[2 * q + 1], hb, lb);
        hp[q] = (unsigned)(unsigned short)ha | ((unsigned)(unsigned short)hb << 16);
        lp[q] = (unsigned)(unsigned short)la | ((unsigned)(unsigned short)lb << 16);
      }
#pragma unroll
      for (int q = 0; q < 4; ++q) {
        *(int4*)&Thi[tid * 40 + q * 8] =
            make_int4(hp[4 * q], hp[4 * q + 1], hp[4 * q + 2], hp[4 * q + 3]);
        *(int4*)&Tlo[tid * 40 + q * 8] =
            make_int4(lp[4 * q], lp[4 * q + 1], lp[4 * q + 2], lp[4 * q + 3]);
      }
    }
    __syncthreads();
    const int nstr = N2 >> 5;
    if (wv < nstr) {
      const int l31 = lane & 31;
      const int h = lane >> 5;
      const int arow = wv * 32 + l31;
#pragma unroll 1
      for (int ct = 0; ct < nstr; ++ct) {
        const int brow = ct * 32 + l31;
        f32x16 acc;
#pragma unroll
        for (int i = 0; i < 16; ++i) acc[i] = 0.f;
#pragma unroll
        for (int ks = 0; ks < 2; ++ks) {
          const int off = ks * 16 + h * 8;
          bf16x8 ahi = *(const bf16x8*)&Thi[arow * 40 + off];
          bf16x8 alo = *(const bf16x8*)&Tlo[arow * 40 + off];
          bf16x8 bhi = *(const bf16x8*)&Thi[brow * 40 + off];
          bf16x8 blo = *(const bf16x8*)&Tlo[brow * 40 + off];
          acc = __builtin_amdgcn_mfma_f32_32x32x16_bf16(ahi, bhi, acc, 0, 0, 0);
          acc = __builtin_amdgcn_mfma_f32_32x32x16_bf16(ahi, blo, acc, 0, 0, 0);
          acc = __builtin_amdgcn_mfma_f32_32x32x16_bf16(alo, bhi, acc, 0, 0, 0);
        }
#pragma unroll
        for (int i = 0; i < 16; ++i) {
          int rr = pbase + 32 + wv * 32 + (i & 3) + 8 * (i >> 2) + 4 * h;
          int cc = pbase + 32 + ct * 32 + l31;
          As[rr][cc] -= acc[i];
        }
      }
    }
    __syncthreads();
  }

  if (wv == 0) red[lane] = lda;
  __syncthreads();
  if (tid == 0) {
    double lsum = 0.0;
    for (int i = 0; i < 64; ++i) lsum += red[i];
    if (j < NCLS) {
      int mj = hist[j];
      double res = 0.0;
      if (mj > 0) {
        double cj = (double)D / ((double)mj * 0.01);
        res = ((double)D * log(cj) + lsum) * (double)mj / (2.0 * (double)Mtot);
      }
      results[j] = res;
    } else {
      double c = (double)D / ((double)Mtot * 0.01);
      results[NCLS] = ((double)D * log(c) + lsum) * 0.5;
    }
  }
}

// ---------------- combine ----------------
__global__ void final_k(const double* __restrict__ results, float* __restrict__ out) {
  if (threadIdx.x == 0 && blockIdx.x == 0) {
    double s = 0.0;
    for (int j = 0; j < NCLS; ++j) s += results[j];
    out[0] = (float)(s - results[NCLS]);
  }
}

extern "C" void kernel_launch(void* const* d_in, const int* in_sizes, int n_in,
                              void* d_out, int out_size, void* d_ws, size_t ws_size,
                              hipStream_t stream) {
  const float* Z = (const float*)d_in[0];
  const int* label = (const int*)d_in[1];
  const int Mtot = in_sizes[1];
  float* out = (float*)d_out;
  const int NB = (Mtot + CHUNK - 1) / CHUNK;

  char* ws = (char*)d_ws;
  int* hist = (int*)(ws + 0);
  int* cstart = (int*)(ws + 256);
  double* results = (double*)(ws + 512);
  int* idxbuf = (int*)(ws + 1024);
  float* partials = (float*)(ws + 1024 + (size_t)Mtot * sizeof(int));
  float* covs = partials + (size_t)NCLS * TSLOT * D * D;
  int* blkhist_t = (int*)partials;  // aliased, dead before cov_k
  int* base_t = blkhist_t + (size_t)NCLS * NB;

  zero_k<<<1, 64, 0, stream>>>(hist);
  hist_blk_k<<<NB, 64, 0, stream>>>(label, Mtot, NB, blkhist_t, hist);
  prefix_k<<<1, 64, 0, stream>>>(hist, cstart);
  base_k<<<NCLS, 64, 0, stream>>>(blkhist_t, cstart, NB, base_t);
  scatter2_k<<<NB, 64, 0, stream>>>(label, Mtot, NB, base_t, idxbuf);
  cov_k<<<NCLS * TSLOT, 1024, 0, stream>>>(Z, idxbuf, hist, cstart, partials);
  reduce_k<<<(D * D) / 256, 256, 0, stream>>>(partials, covs);
  chol_k<<<NCLS + 1, 256, 0, stream>>>(covs, hist, Mtot, results);
  final_k<<<1, 64, 0, stream>>>(results, out);
}